// Round 1
// baseline (563.173 us; speedup 1.0000x reference)
//
#include <hip/hip_runtime.h>

#define SEQ 2048
#define DM  768
#define ST  100
#define KF  24

// ---------------------------------------------------------------------------
// Precompute W'[j][d] = sum_k (C[j,k] + C[j,k+24]) * Mf[k,d]   (100 x 768)
//            e[d]     = sum_k (Dv[k] + Dv[k+24])   * Mf[k,d]   (768)
// ---------------------------------------------------------------------------
__global__ void precompute_k(const float* __restrict__ C, const float* __restrict__ Dv,
                             const float* __restrict__ Mf,
                             float* __restrict__ Wp, float* __restrict__ evec) {
    int tid = blockIdx.x * blockDim.x + threadIdx.x;
    if (tid < ST * DM) {
        int j = tid / DM, d = tid % DM;
        float s = 0.f;
#pragma unroll
        for (int k = 0; k < KF; ++k)
            s += (C[j * 2 * KF + k] + C[j * 2 * KF + KF + k]) * Mf[k * DM + d];
        Wp[j * DM + d] = s;
    }
    if (tid < DM) {
        float s = 0.f;
#pragma unroll
        for (int k = 0; k < KF; ++k)
            s += (Dv[k] + Dv[KF + k]) * Mf[k * DM + tid];
        evec[tid] = s;
    }
}

// ---------------------------------------------------------------------------
// GEMM: ut[d][s] = sum_i x[s][i] * M[i][d]   (output TRANSPOSED: channel-major)
// fp32 vector GEMM, 64x64 tile, BK=16, 256 threads, 4x4 microtile.
// ---------------------------------------------------------------------------
#define BM 64
#define BN 64
#define BK 16
__global__ __launch_bounds__(256) void gemm_xt(const float* __restrict__ A,
                                               const float* __restrict__ B,
                                               float* __restrict__ ut) {
    __shared__ float As[BK][BM + 1];
    __shared__ float Bs[BK][BN];
    int tid = threadIdx.x;
    int bm = blockIdx.x * BM;   // seq tile
    int bn = blockIdx.y * BN;   // channel tile
    int tx = tid & 15, ty = tid >> 4;
    float acc[4][4] = {};
    for (int k0 = 0; k0 < DM; k0 += BK) {
#pragma unroll
        for (int i = 0; i < 4; ++i) {
            int idx = tid + i * 256;
            int r = idx >> 4, c = idx & 15;          // A tile 64x16
            As[c][r] = A[(bm + r) * DM + k0 + c];
        }
#pragma unroll
        for (int i = 0; i < 4; ++i) {
            int idx = tid + i * 256;
            int r = idx >> 6, c = idx & 63;          // B tile 16x64
            Bs[r][c] = B[(k0 + r) * DM + bn + c];
        }
        __syncthreads();
#pragma unroll
        for (int kk = 0; kk < BK; ++kk) {
            float a[4], b[4];
#pragma unroll
            for (int i = 0; i < 4; ++i) a[i] = As[kk][tx * 4 + i];
#pragma unroll
            for (int j = 0; j < 4; ++j) b[j] = Bs[kk][ty * 4 + j];
#pragma unroll
            for (int j = 0; j < 4; ++j)
#pragma unroll
                for (int i = 0; i < 4; ++i) acc[j][i] += a[i] * b[j];
        }
        __syncthreads();
    }
    // store transposed: ut[(bn + ty*4 + j) * SEQ + bm + tx*4 + i]
#pragma unroll
    for (int j = 0; j < 4; ++j) {
        float4 v = make_float4(acc[j][0], acc[j][1], acc[j][2], acc[j][3]);
        *(float4*)&ut[(bn + ty * 4 + j) * SEQ + bm + tx * 4] = v;
    }
}

// ---------------------------------------------------------------------------
// Scan: one wave per channel d. Lane l owns states l and l+64 (l+64<100).
// Per step: broadcast u_t, update h, partial dot, butterfly-reduce, keep
// result in the lane whose index == step, store 64 results per outer iter.
// ---------------------------------------------------------------------------
__global__ __launch_bounds__(64) void scan_k(const float* __restrict__ ut,
                                             const float* __restrict__ Av,
                                             const float* __restrict__ Bv,
                                             const float* __restrict__ Wp,
                                             const float* __restrict__ evec,
                                             float* __restrict__ out) {
    int d = blockIdx.x;
    int l = threadIdx.x;
    const float* u = ut + d * SEQ;
    float A1 = Av[l], B1 = Bv[l], c1 = Wp[l * DM + d];
    float A2 = 0.f, B2 = 0.f, c2 = 0.f;
    if (l + 64 < ST) {
        A2 = Av[l + 64]; B2 = Bv[l + 64]; c2 = Wp[(l + 64) * DM + d];
    }
    float e = evec[d];
    float h1 = 0.f, h2 = 0.f;
    for (int base = 0; base < SEQ; base += 64) {
        float ur = u[base + l];        // coalesced: 64 timesteps
        float res = 0.f;
#pragma unroll
        for (int t = 0; t < 64; ++t) {
            float uv = __shfl(ur, t);
            h1 = h1 * A1 + uv * B1;
            h2 = h2 * A2 + uv * B2;
            float p = h1 * c1 + h2 * c2;
#pragma unroll
            for (int m = 1; m < 64; m <<= 1) p += __shfl_xor(p, m);
            float val = p + e * uv;
            res = (l == t) ? val : res;
        }
        out[(base + l) * DM + d] = res;   // each lane writes its own timestep
    }
}

extern "C" void kernel_launch(void* const* d_in, const int* in_sizes, int n_in,
                              void* d_out, int out_size, void* d_ws, size_t ws_size,
                              hipStream_t stream) {
    const float* x  = (const float*)d_in[0];
    // d_in[1] = input_pos (unused)
    const float* Mi = (const float*)d_in[2];
    const float* Mf = (const float*)d_in[3];
    const float* Av = (const float*)d_in[4];
    const float* Bv = (const float*)d_in[5];
    const float* C  = (const float*)d_in[6];
    const float* Dv = (const float*)d_in[7];
    float* out = (float*)d_out;

    float* ut = (float*)d_ws;            // 768*2048 floats
    float* Wp = ut + DM * SEQ;           // 100*768
    float* ev = Wp + ST * DM;            // 768

    precompute_k<<<(ST * DM + 255) / 256, 256, 0, stream>>>(C, Dv, Mf, Wp, ev);
    dim3 g(SEQ / BM, DM / BN);
    gemm_xt<<<g, 256, 0, stream>>>(x, Mi, ut);
    scan_k<<<DM, 64, 0, stream>>>(ut, Av, Bv, Wp, ev, out);
}

// Round 2
// 242.319 us; speedup vs baseline: 2.3241x; 2.3241x over previous
//
#include <hip/hip_runtime.h>
#include <math.h>

#define SEQ   2048
#define DM    768
#define ST    100
#define KF    24
#define CHUNK 512
#define NCH   4      // SEQ / CHUNK
#define RT    8      // timesteps per lane (CHUNK = 64 * RT)

// ---------------------------------------------------------------------------
// Precompute W'[j][d] = sum_k (C[j,k] + C[j,k+24]) * Mf[k,d]   (100 x 768)
//            e[d]     = sum_k (Dv[k] + Dv[k+24])   * Mf[k,d]   (768)
// ---------------------------------------------------------------------------
__global__ void precompute_k(const float* __restrict__ C, const float* __restrict__ Dv,
                             const float* __restrict__ Mf,
                             float* __restrict__ Wp, float* __restrict__ evec) {
    int tid = blockIdx.x * blockDim.x + threadIdx.x;
    if (tid < ST * DM) {
        int j = tid / DM, d = tid % DM;
        float s = 0.f;
#pragma unroll
        for (int k = 0; k < KF; ++k)
            s += (C[j * 2 * KF + k] + C[j * 2 * KF + KF + k]) * Mf[k * DM + d];
        Wp[j * DM + d] = s;
    }
    if (tid < DM) {
        float s = 0.f;
#pragma unroll
        for (int k = 0; k < KF; ++k)
            s += (Dv[k] + Dv[KF + k]) * Mf[k * DM + tid];
        evec[tid] = s;
    }
}

// ---------------------------------------------------------------------------
// GEMM: ut[d][s] = sum_i x[s][i] * M[i][d]   (channel-major output)
// ---------------------------------------------------------------------------
#define BM 64
#define BN 64
#define BK 16
__global__ __launch_bounds__(256) void gemm_xt(const float* __restrict__ A,
                                               const float* __restrict__ B,
                                               float* __restrict__ ut) {
    __shared__ float As[BK][BM + 1];
    __shared__ float Bs[BK][BN];
    int tid = threadIdx.x;
    int bm = blockIdx.x * BM;   // seq tile
    int bn = blockIdx.y * BN;   // channel tile
    int tx = tid & 15, ty = tid >> 4;
    float acc[4][4] = {};
    for (int k0 = 0; k0 < DM; k0 += BK) {
#pragma unroll
        for (int i = 0; i < 4; ++i) {
            int idx = tid + i * 256;
            int r = idx >> 4, c = idx & 15;
            As[c][r] = A[(bm + r) * DM + k0 + c];
        }
#pragma unroll
        for (int i = 0; i < 4; ++i) {
            int idx = tid + i * 256;
            int r = idx >> 6, c = idx & 63;
            Bs[r][c] = B[(k0 + r) * DM + bn + c];
        }
        __syncthreads();
#pragma unroll
        for (int kk = 0; kk < BK; ++kk) {
            float a[4], b[4];
#pragma unroll
            for (int i = 0; i < 4; ++i) a[i] = As[kk][tx * 4 + i];
#pragma unroll
            for (int j = 0; j < 4; ++j) b[j] = Bs[kk][ty * 4 + j];
#pragma unroll
            for (int j = 0; j < 4; ++j)
#pragma unroll
                for (int i = 0; i < 4; ++i) acc[j][i] += a[i] * b[j];
        }
        __syncthreads();
    }
#pragma unroll
    for (int j = 0; j < 4; ++j) {
        float4 v = make_float4(acc[j][0], acc[j][1], acc[j][2], acc[j][3]);
        *(float4*)&ut[(bn + ty * 4 + j) * SEQ + bm + tx * 4] = v;
    }
}

// ---------------------------------------------------------------------------
// S1: chunk-local scan. block = 1 wave = (channel d, chunk c).
// Lane l owns timesteps c*512 + l*8 .. +7. Serial loop over the 100 states:
// local 8-step affine compose -> 6-step wave scan -> expand -> accumulate y.
// Writes y_local + e*u (channel-major) and the chunk-final 100-state vector.
// ---------------------------------------------------------------------------
__global__ __launch_bounds__(64) void s1_scan(const float* __restrict__ ut,
                                              const float* __restrict__ Av,
                                              const float* __restrict__ Bv,
                                              const float* __restrict__ Wp,
                                              const float* __restrict__ evec,
                                              float* __restrict__ yb,
                                              float* __restrict__ hf) {
    const int d = blockIdx.x, c = blockIdx.y, l = threadIdx.x;
    const float* u = ut + d * SEQ + c * CHUNK + l * RT;
    float uu[RT];
    {
        float4 v0 = *(const float4*)u;
        float4 v1 = *(const float4*)(u + 4);
        uu[0] = v0.x; uu[1] = v0.y; uu[2] = v0.z; uu[3] = v0.w;
        uu[4] = v1.x; uu[5] = v1.y; uu[6] = v1.z; uu[7] = v1.w;
    }
    float e = evec[d];
    float alo = Av[l], blo = Bv[l], wlo = Wp[l * DM + d];
    float ahi = 0.f, bhi = 0.f, whi = 0.f;
    if (l < ST - 64) { ahi = Av[l + 64]; bhi = Bv[l + 64]; whi = Wp[(l + 64) * DM + d]; }
    float t2 = alo * alo, t4 = t2 * t2;  float a8lo = t4 * t4;
    float s2 = ahi * ahi, s4 = s2 * s2;  float a8hi = s4 * s4;

    float y[RT];
#pragma unroll
    for (int i = 0; i < RT; ++i) y[i] = 0.f;
    float hflo = 0.f, hfhi = 0.f;

#define PROCESS(AJ, A8J, BJ, WJ, KEEP, JIDX)                                   \
    {                                                                          \
        float tb[RT];                                                          \
        _Pragma("unroll")                                                      \
        for (int i = 0; i < RT; ++i) tb[i] = (BJ) * uu[i];                     \
        float hloc = tb[0];                                                    \
        _Pragma("unroll")                                                      \
        for (int i = 1; i < RT; ++i) hloc = fmaf((AJ), hloc, tb[i]);           \
        float sa = (A8J), sb = hloc;                                           \
        _Pragma("unroll")                                                      \
        for (int s = 1; s < 64; s <<= 1) {                                     \
            float pa = __shfl_up(sa, s);                                       \
            float pb = __shfl_up(sb, s);                                       \
            float nb = fmaf(sa, pb, sb);                                       \
            float na = sa * pa;                                                \
            sb = (l >= s) ? nb : sb;                                           \
            sa = (l >= s) ? na : sa;                                           \
        }                                                                      \
        float pin = __shfl_up(sb, 1);                                          \
        float h = (l == 0) ? 0.f : pin;                                        \
        _Pragma("unroll")                                                      \
        for (int i = 0; i < RT; ++i) {                                         \
            h = fmaf((AJ), h, tb[i]);                                          \
            y[i] = fmaf(h, (WJ), y[i]);                                        \
        }                                                                      \
        float ff = __shfl(sb, 63);                                             \
        KEEP = (l == (JIDX)) ? ff : KEEP;                                      \
    }

#pragma unroll 2
    for (int j = 0; j < 64; ++j) {
        float aj  = __shfl(alo, j);
        float a8j = __shfl(a8lo, j);
        float bj  = __shfl(blo, j);
        float wj  = __shfl(wlo, j);
        PROCESS(aj, a8j, bj, wj, hflo, j)
    }
#pragma unroll 2
    for (int j = 0; j < ST - 64; ++j) {
        float aj  = __shfl(ahi, j);
        float a8j = __shfl(a8hi, j);
        float bj  = __shfl(bhi, j);
        float wj  = __shfl(whi, j);
        PROCESS(aj, a8j, bj, wj, hfhi, j)
    }
#undef PROCESS

    // write y_local + e*u (channel-major, coalesced)
    float* yo = yb + d * SEQ + c * CHUNK + l * RT;
    float4 o0 = make_float4(fmaf(e, uu[0], y[0]), fmaf(e, uu[1], y[1]),
                            fmaf(e, uu[2], y[2]), fmaf(e, uu[3], y[3]));
    float4 o1 = make_float4(fmaf(e, uu[4], y[4]), fmaf(e, uu[5], y[5]),
                            fmaf(e, uu[6], y[6]), fmaf(e, uu[7], y[7]));
    *(float4*)yo = o0;
    *(float4*)(yo + 4) = o1;

    float* hfo = hf + (d * NCH + c) * ST;
    hfo[l] = hflo;
    if (l < ST - 64) hfo[64 + l] = hfhi;
}

// ---------------------------------------------------------------------------
// S2: inter-chunk stitch. hs[c] = A^512 * hs[c-1] + hfin[c-1]; g = w_j * hs.
// ---------------------------------------------------------------------------
__global__ void s2_link(const float* __restrict__ hf, const float* __restrict__ Av,
                        const float* __restrict__ Wp, float* __restrict__ g) {
    int d = blockIdx.x, j = threadIdx.x;
    if (j >= ST) return;
    float a = Av[j];
    float p = a;
#pragma unroll
    for (int i = 0; i < 9; ++i) p = p * p;     // A^512
    float w = Wp[j * DM + d];
    float hs = 0.f;
#pragma unroll
    for (int c = 0; c < NCH; ++c) {
        g[(d * NCH + c) * ST + j] = w * hs;
        hs = fmaf(p, hs, hf[(d * NCH + c) * ST + j]);
    }
}

// ---------------------------------------------------------------------------
// S3: add inter-chunk correction: y[t0+tau] += sum_j A_j^(tau+1) * g_j.
// ---------------------------------------------------------------------------
__global__ __launch_bounds__(64) void s3_fix(float* __restrict__ yb,
                                             const float* __restrict__ g,
                                             const float* __restrict__ Av) {
    int d = blockIdx.x, c = blockIdx.y, l = threadIdx.x;
    const float* gc = g + (d * NCH + c) * ST;
    float glo = gc[l];
    float ghi = (l < ST - 64) ? gc[64 + l] : 0.f;
    float alo = Av[l];
    float ahi = (l < ST - 64) ? Av[64 + l] : 1.f;
    float lalo = log2f(alo);
    float lahi = log2f(ahi);
    float corr[RT];
#pragma unroll
    for (int i = 0; i < RT; ++i) corr[i] = 0.f;
    float tbase = (float)(l * RT + 1);

#pragma unroll 2
    for (int j = 0; j < 64; ++j) {
        float aj = __shfl(alo, j);
        float la = __shfl(lalo, j);
        float gj = __shfl(glo, j);
        float q = exp2f(tbase * la) * gj;
#pragma unroll
        for (int i = 0; i < RT; ++i) { corr[i] += q; q *= aj; }
    }
#pragma unroll 2
    for (int j = 0; j < ST - 64; ++j) {
        float aj = __shfl(ahi, j);
        float la = __shfl(lahi, j);
        float gj = __shfl(ghi, j);
        float q = exp2f(tbase * la) * gj;
#pragma unroll
        for (int i = 0; i < RT; ++i) { corr[i] += q; q *= aj; }
    }

    float* yo = yb + d * SEQ + c * CHUNK + l * RT;
    float4 v0 = *(float4*)yo;
    float4 v1 = *(float4*)(yo + 4);
    v0.x += corr[0]; v0.y += corr[1]; v0.z += corr[2]; v0.w += corr[3];
    v1.x += corr[4]; v1.y += corr[5]; v1.z += corr[6]; v1.w += corr[7];
    *(float4*)yo = v0;
    *(float4*)(yo + 4) = v1;
}

// ---------------------------------------------------------------------------
// S4: transpose yb (d-major) -> out (t-major). 64x64 LDS tiles.
// ---------------------------------------------------------------------------
__global__ __launch_bounds__(256) void s4_tr(const float* __restrict__ yb,
                                             float* __restrict__ out) {
    __shared__ float tile[64][65];
    int t0 = blockIdx.x * 64, d0 = blockIdx.y * 64;
    int tx = threadIdx.x & 63, ty = threadIdx.x >> 6;
#pragma unroll
    for (int i = ty; i < 64; i += 4)
        tile[i][tx] = yb[(d0 + i) * SEQ + t0 + tx];
    __syncthreads();
#pragma unroll
    for (int i = ty; i < 64; i += 4)
        out[(t0 + i) * DM + d0 + tx] = tile[tx][i];
}

extern "C" void kernel_launch(void* const* d_in, const int* in_sizes, int n_in,
                              void* d_out, int out_size, void* d_ws, size_t ws_size,
                              hipStream_t stream) {
    const float* x  = (const float*)d_in[0];
    const float* Mi = (const float*)d_in[2];
    const float* Mf = (const float*)d_in[3];
    const float* Av = (const float*)d_in[4];
    const float* Bv = (const float*)d_in[5];
    const float* C  = (const float*)d_in[6];
    const float* Dv = (const float*)d_in[7];
    float* out = (float*)d_out;

    float* ut = (float*)d_ws;            // 768*2048
    float* Wp = ut + DM * SEQ;           // 100*768
    float* ev = Wp + ST * DM;            // 768
    float* yb = ev + DM;                 // 768*2048
    float* hf = yb + DM * SEQ;           // 768*4*100
    float* g  = hf + DM * NCH * ST;      // 768*4*100

    precompute_k<<<(ST * DM + 255) / 256, 256, 0, stream>>>(C, Dv, Mf, Wp, ev);
    gemm_xt<<<dim3(SEQ / BM, DM / BN), 256, 0, stream>>>(x, Mi, ut);
    s1_scan<<<dim3(DM, NCH), 64, 0, stream>>>(ut, Av, Bv, Wp, ev, yb, hf);
    s2_link<<<DM, 128, 0, stream>>>(hf, Av, Wp, g);
    s3_fix<<<dim3(DM, NCH), 64, 0, stream>>>(yb, g, Av);
    s4_tr<<<dim3(SEQ / 64, DM / 64), 256, 0, stream>>>(yb, out);
}

// Round 3
// 200.628 us; speedup vs baseline: 2.8070x; 1.2078x over previous
//
#include <hip/hip_runtime.h>
#include <math.h>

#define SEQ   2048
#define DM    768
#define ST    100
#define KF    24
#define CHUNK 512
#define NCH   4      // SEQ / CHUNK
#define RT    8      // timesteps per lane
#define GK    2304   // 3 * DM  (bf16x3 split K)
#define GBK   32

using short8  = __attribute__((ext_vector_type(8))) short;
using float4v = __attribute__((ext_vector_type(4))) float;

__device__ __forceinline__ unsigned short bf16_rn(float x) {
    unsigned int u = __float_as_uint(x);
    unsigned int r = u + 0x7FFFu + ((u >> 16) & 1u);
    return (unsigned short)(r >> 16);
}
__device__ __forceinline__ float rlane(float v, int j) {
    return __int_as_float(__builtin_amdgcn_readlane(__float_as_int(v), j));
}

// ---------------------------------------------------------------------------
// prep: one kernel, three block ranges.
//  [0,144)        : Mbig[d][k] = [Mih^T | Mih^T | Mil^T]  (64x64 LDS transpose)
//  [144,3216)     : Xbig[s][k] = [xh | xl | xh]
//  [3216,3516)    : WpT[d][j] = sum_k (C[j,k]+C[j,k+24])*Mf[k,d];  ev[d]
// ---------------------------------------------------------------------------
__global__ __launch_bounds__(256) void prep(const float* __restrict__ x,
                                            const float* __restrict__ Mi,
                                            const float* __restrict__ C,
                                            const float* __restrict__ Dv,
                                            const float* __restrict__ Mf,
                                            unsigned short* __restrict__ Mbig,
                                            unsigned short* __restrict__ Xbig,
                                            float* __restrict__ WpT,
                                            float* __restrict__ evec) {
    __shared__ float tl[64][65];
    int bid = blockIdx.x, t = threadIdx.x;
    if (bid < 144) {
        int i0 = (bid / 12) * 64, d0 = (bid % 12) * 64;
        int tx = t & 63, ty = t >> 6;
#pragma unroll
        for (int r = ty; r < 64; r += 4)
            tl[r][tx] = Mi[(i0 + r) * DM + d0 + tx];
        __syncthreads();
#pragma unroll
        for (int r = ty; r < 64; r += 4) {
            float v = tl[tx][r];                       // Mi[i0+tx][d0+r]
            unsigned short h = bf16_rn(v);
            float hf = __uint_as_float(((unsigned int)h) << 16);
            unsigned short lo = bf16_rn(v - hf);
            unsigned short* row = Mbig + (size_t)(d0 + r) * GK + i0 + tx;
            row[0] = h; row[DM] = h; row[2 * DM] = lo;
        }
    } else if (bid < 144 + 3072) {
        int p = (bid - 144) * 256 + t;                 // pair index < 786432
        int s = p / (DM / 2), i = (p % (DM / 2)) * 2;
        float2 v = *(const float2*)&x[(size_t)s * DM + i];
        unsigned short h0 = bf16_rn(v.x);
        float hf0 = __uint_as_float(((unsigned int)h0) << 16);
        unsigned short l0 = bf16_rn(v.x - hf0);
        unsigned short h1 = bf16_rn(v.y);
        float hf1 = __uint_as_float(((unsigned int)h1) << 16);
        unsigned short l1 = bf16_rn(v.y - hf1);
        unsigned short* row = Xbig + (size_t)s * GK + i;
        ushort2 hh; hh.x = h0; hh.y = h1;
        ushort2 ll; ll.x = l0; ll.y = l1;
        *(ushort2*)(row)          = hh;
        *(ushort2*)(row + DM)     = ll;
        *(ushort2*)(row + 2 * DM) = hh;
    } else {
        int tid = (bid - 3216) * 256 + t;
        if (tid < ST * DM) {
            int d = tid / ST, j = tid % ST;
            float s = 0.f;
#pragma unroll
            for (int k = 0; k < KF; ++k)
                s += (C[j * 2 * KF + k] + C[j * 2 * KF + KF + k]) * Mf[k * DM + d];
            WpT[tid] = s;
        }
        if (tid < DM) {
            float s = 0.f;
#pragma unroll
            for (int k = 0; k < KF; ++k)
                s += (Dv[k] + Dv[KF + k]) * Mf[k * DM + tid];
            evec[tid] = s;
        }
    }
}

// ---------------------------------------------------------------------------
// MFMA GEMM: ut[d][s] = sum_k Mbig[d][k]*Xbig[s][k]  (= x @ M_inputs, fp32-split)
// 128x128 tile, BK=32, 4 waves (2x2), each wave 4x4 mfma_f32_16x16x32_bf16.
// ---------------------------------------------------------------------------
__global__ __launch_bounds__(256) void gemm_mfma(const unsigned short* __restrict__ Mbig,
                                                 const unsigned short* __restrict__ Xbig,
                                                 float* __restrict__ ut) {
    __shared__ unsigned short As[128 * GBK];   // [d-row][k]
    __shared__ unsigned short Bs[128 * GBK];   // [s-row][k]
    int t = threadIdx.x;
    int d0 = blockIdx.x * 128;
    int s0 = blockIdx.y * 128;
    int wave = t >> 6, lane = t & 63;
    int wm = (wave & 1) * 64, wn = (wave >> 1) * 64;
    int m16 = lane & 15, quad = lane >> 4;
    float4v acc[4][4] = {};
    for (int k0 = 0; k0 < GK; k0 += GBK) {
#pragma unroll
        for (int it = 0; it < 2; ++it) {
            int idx = t + it * 256;
            int row = idx >> 2, koff = (idx & 3) * 8;
            *(uint4*)&As[row * GBK + koff] = *(const uint4*)&Mbig[(size_t)(d0 + row) * GK + k0 + koff];
            *(uint4*)&Bs[row * GBK + koff] = *(const uint4*)&Xbig[(size_t)(s0 + row) * GK + k0 + koff];
        }
        __syncthreads();
        short8 af[4], bf[4];
#pragma unroll
        for (int mt = 0; mt < 4; ++mt)
            af[mt] = *(short8*)&As[(wm + mt * 16 + m16) * GBK + quad * 8];
#pragma unroll
        for (int nt = 0; nt < 4; ++nt)
            bf[nt] = *(short8*)&Bs[(wn + nt * 16 + m16) * GBK + quad * 8];
#pragma unroll
        for (int mt = 0; mt < 4; ++mt)
#pragma unroll
            for (int nt = 0; nt < 4; ++nt)
                acc[mt][nt] = __builtin_amdgcn_mfma_f32_16x16x32_bf16(af[mt], bf[nt], acc[mt][nt], 0, 0, 0);
        __syncthreads();
    }
    // D[row=quad*4+i][col=m16]: row -> d, col -> s  (coalesced dword stores)
#pragma unroll
    for (int mt = 0; mt < 4; ++mt)
#pragma unroll
        for (int nt = 0; nt < 4; ++nt) {
            int dd = d0 + wm + mt * 16 + quad * 4;
            int ss = s0 + wn + nt * 16 + m16;
#pragma unroll
            for (int i = 0; i < 4; ++i)
                ut[(size_t)(dd + i) * SEQ + ss] = acc[mt][nt][i];
        }
}

// ---------------------------------------------------------------------------
// s1f: fused chunk scan + inter-chunk stitch + correction.
// 768 blocks x 256 threads; wave c handles chunk c of channel blockIdx.x.
// ---------------------------------------------------------------------------
__global__ __launch_bounds__(256) void s1f(const float* __restrict__ ut,
                                           const float* __restrict__ Av,
                                           const float* __restrict__ Bv,
                                           const float* __restrict__ WpT,
                                           const float* __restrict__ evec,
                                           float* __restrict__ yb) {
    __shared__ float hfL[NCH][128];
    const int d = blockIdx.x;
    const int c = threadIdx.x >> 6;
    const int l = threadIdx.x & 63;
    const float* u = ut + (size_t)d * SEQ + c * CHUNK + l * RT;
    float uu[RT];
    {
        float4 v0 = *(const float4*)u;
        float4 v1 = *(const float4*)(u + 4);
        uu[0] = v0.x; uu[1] = v0.y; uu[2] = v0.z; uu[3] = v0.w;
        uu[4] = v1.x; uu[5] = v1.y; uu[6] = v1.z; uu[7] = v1.w;
    }
    float e = evec[d];
    bool hiA = (l < ST - 64);
    float alo = Av[l], blo = Bv[l], wlo = WpT[d * ST + l];
    float ahi = hiA ? Av[l + 64] : 0.f;
    float bhi = hiA ? Bv[l + 64] : 0.f;
    float whi = hiA ? WpT[d * ST + 64 + l] : 0.f;
    float t2 = alo * alo, t4 = t2 * t2;  float a8lo = t4 * t4;
    float s2 = ahi * ahi, s4 = s2 * s2;  float a8hi = s4 * s4;

    float y[RT];
#pragma unroll
    for (int i = 0; i < RT; ++i) y[i] = 0.f;
    float hflo = 0.f, hfhi = 0.f;

#define PROCESS(AJ, A8J, BJ, WJ, KEEP, JIDX)                                   \
    {                                                                          \
        float tb[RT];                                                          \
        _Pragma("unroll")                                                      \
        for (int i = 0; i < RT; ++i) tb[i] = (BJ) * uu[i];                     \
        float hloc = tb[0];                                                    \
        _Pragma("unroll")                                                      \
        for (int i = 1; i < RT; ++i) hloc = fmaf((AJ), hloc, tb[i]);           \
        float sa = (A8J), sb = hloc;                                           \
        _Pragma("unroll")                                                      \
        for (int s = 1; s < 64; s <<= 1) {                                     \
            float pa = __shfl_up(sa, s);                                       \
            float pb = __shfl_up(sb, s);                                       \
            float nb = fmaf(sa, pb, sb);                                       \
            float na = sa * pa;                                                \
            sb = (l >= s) ? nb : sb;                                           \
            sa = (l >= s) ? na : sa;                                           \
        }                                                                      \
        float pin = __shfl_up(sb, 1);                                          \
        float h = (l == 0) ? 0.f : pin;                                        \
        _Pragma("unroll")                                                      \
        for (int i = 0; i < RT; ++i) {                                         \
            h = fmaf((AJ), h, tb[i]);                                          \
            y[i] = fmaf(h, (WJ), y[i]);                                        \
        }                                                                      \
        float ff = rlane(sb, 63);                                              \
        KEEP = (l == (JIDX)) ? ff : KEEP;                                      \
    }

#pragma unroll 2
    for (int j = 0; j < 64; ++j) {
        float aj  = rlane(alo, j);
        float a8j = rlane(a8lo, j);
        float bj  = rlane(blo, j);
        float wj  = rlane(wlo, j);
        PROCESS(aj, a8j, bj, wj, hflo, j)
    }
#pragma unroll 2
    for (int j = 0; j < ST - 64; ++j) {
        float aj  = rlane(ahi, j);
        float a8j = rlane(a8hi, j);
        float bj  = rlane(bhi, j);
        float wj  = rlane(whi, j);
        PROCESS(aj, a8j, bj, wj, hfhi, j)
    }
#undef PROCESS

    hfL[c][l] = hflo;
    hfL[c][64 + l] = hfhi;        // 0 for inactive lanes
    __syncthreads();

    // inter-chunk state prefix: hs = sum_{c'<c} p^(c-1-c') hf[c']
    float plo = alo, phi = ahi;
#pragma unroll
    for (int i = 0; i < 9; ++i) { plo *= plo; phi *= phi; }   // A^512
    float hslo = 0.f, hshi = 0.f;
    for (int cc = 0; cc < c; ++cc) {
        hslo = fmaf(plo, hslo, hfL[cc][l]);
        hshi = fmaf(phi, hshi, hfL[cc][64 + l]);
    }
    float glo = wlo * hslo;
    float ghi = whi * hshi;

    float corr[RT];
#pragma unroll
    for (int i = 0; i < RT; ++i) corr[i] = 0.f;
    if (c > 0) {
        float lalo = log2f(alo);
        float lahi = hiA ? log2f(ahi) : 0.f;
        float tb = (float)(l * RT + 1);
#pragma unroll 2
        for (int j = 0; j < 64; ++j) {
            float aj = rlane(alo, j);
            float la = rlane(lalo, j);
            float gj = rlane(glo, j);
            float q = exp2f(tb * la) * gj;
#pragma unroll
            for (int i = 0; i < RT; ++i) { corr[i] += q; q *= aj; }
        }
#pragma unroll 2
        for (int j = 0; j < ST - 64; ++j) {
            float aj = rlane(ahi, j);
            float la = rlane(lahi, j);
            float gj = rlane(ghi, j);
            float q = exp2f(tb * la) * gj;
#pragma unroll
            for (int i = 0; i < RT; ++i) { corr[i] += q; q *= aj; }
        }
    }

    float* yo = yb + (size_t)d * SEQ + c * CHUNK + l * RT;
    float4 o0 = make_float4(fmaf(e, uu[0], y[0] + corr[0]), fmaf(e, uu[1], y[1] + corr[1]),
                            fmaf(e, uu[2], y[2] + corr[2]), fmaf(e, uu[3], y[3] + corr[3]));
    float4 o1 = make_float4(fmaf(e, uu[4], y[4] + corr[4]), fmaf(e, uu[5], y[5] + corr[5]),
                            fmaf(e, uu[6], y[6] + corr[6]), fmaf(e, uu[7], y[7] + corr[7]));
    *(float4*)yo = o0;
    *(float4*)(yo + 4) = o1;
}

// ---------------------------------------------------------------------------
// s4: transpose yb (d-major) -> out (t-major). 64x64 LDS tiles.
// ---------------------------------------------------------------------------
__global__ __launch_bounds__(256) void s4_tr(const float* __restrict__ yb,
                                             float* __restrict__ out) {
    __shared__ float tile[64][65];
    int t0 = blockIdx.x * 64, d0 = blockIdx.y * 64;
    int tx = threadIdx.x & 63, ty = threadIdx.x >> 6;
#pragma unroll
    for (int i = ty; i < 64; i += 4)
        tile[i][tx] = yb[(size_t)(d0 + i) * SEQ + t0 + tx];
    __syncthreads();
#pragma unroll
    for (int i = ty; i < 64; i += 4)
        out[(size_t)(t0 + i) * DM + d0 + tx] = tile[tx][i];
}

extern "C" void kernel_launch(void* const* d_in, const int* in_sizes, int n_in,
                              void* d_out, int out_size, void* d_ws, size_t ws_size,
                              hipStream_t stream) {
    const float* x  = (const float*)d_in[0];
    const float* Mi = (const float*)d_in[2];
    const float* Mf = (const float*)d_in[3];
    const float* Av = (const float*)d_in[4];
    const float* Bv = (const float*)d_in[5];
    const float* C  = (const float*)d_in[6];
    const float* Dv = (const float*)d_in[7];
    float* out = (float*)d_out;

    float* ut  = (float*)d_ws;                          // DM*SEQ f32
    float* WpT = ut + (size_t)DM * SEQ;                 // DM*ST f32 (transposed: [d][j])
    float* ev  = WpT + ST * DM;                         // DM f32
    unsigned short* Mbig = (unsigned short*)(ev + DM);  // DM*GK bf16
    unsigned short* Xbig = Mbig + (size_t)DM * GK;      // SEQ*GK bf16
    float* yb = (float*)Xbig;                           // aliases Xbig (dead after gemm)

    prep<<<3516, 256, 0, stream>>>(x, Mi, C, Dv, Mf, Mbig, Xbig, WpT, ev);
    gemm_mfma<<<dim3(DM / 128, SEQ / 128), 256, 0, stream>>>(Mbig, Xbig, ut);
    s1f<<<DM, 256, 0, stream>>>(ut, Av, Bv, WpT, ev, yb);
    s4_tr<<<dim3(SEQ / 64, DM / 64), 256, 0, stream>>>(yb, out);
}

// Round 4
// 178.316 us; speedup vs baseline: 3.1583x; 1.1251x over previous
//
#include <hip/hip_runtime.h>

#define SEQ   2048
#define DM    768
#define ST    100
#define KF    24
#define L64   64
#define NC    32      // SEQ / L64
#define KJ    128     // padded state dim for inter-GEMM K
#define NJ    112     // padded state dim for hloc-GEMM N
#define GK    2304    // 3 * DM  (bf16x3 split K for input GEMM)
#define GBK   32
#define APAD  40      // LDS row pad for gemm staging (32 + 8)

using short8  = __attribute__((ext_vector_type(8))) short;
using float4v = __attribute__((ext_vector_type(4))) float;

__device__ __forceinline__ unsigned short bf16_rn(float x) {
    unsigned int u = __float_as_uint(x);
    unsigned int r = u + 0x7FFFu + ((u >> 16) & 1u);
    return (unsigned short)(r >> 16);
}
__device__ __forceinline__ float bf2f(unsigned short h) {
    return __uint_as_float(((unsigned int)h) << 16);
}

// ---------------------------------------------------------------------------
// prep: block ranges:
//  [0,144)     Mbig[d][k] = [Mih^T | Mih^T | Mil^T]
//  [144,3216)  Xbig[s][k] = [xh | xl | xh]
//  [3216,3516) WpT[d][j] = sum_k (C[j,k]+C[j,k+24])*Mf[k,d];  ev[d]
//  [3516]      Apow[delta][j] = A_j^delta, delta = 0..64
// ---------------------------------------------------------------------------
__global__ __launch_bounds__(256) void prep(const float* __restrict__ x,
                                            const float* __restrict__ Mi,
                                            const float* __restrict__ C,
                                            const float* __restrict__ Dv,
                                            const float* __restrict__ Mf,
                                            const float* __restrict__ Av,
                                            unsigned short* __restrict__ Mbig,
                                            unsigned short* __restrict__ Xbig,
                                            float* __restrict__ WpT,
                                            float* __restrict__ evec,
                                            float* __restrict__ Apow) {
    __shared__ float tl[64][65];
    int bid = blockIdx.x, t = threadIdx.x;
    if (bid < 144) {
        int i0 = (bid / 12) * 64, d0 = (bid % 12) * 64;
        int tx = t & 63, ty = t >> 6;
#pragma unroll
        for (int r = ty; r < 64; r += 4)
            tl[r][tx] = Mi[(i0 + r) * DM + d0 + tx];
        __syncthreads();
#pragma unroll
        for (int r = ty; r < 64; r += 4) {
            float v = tl[tx][r];                       // Mi[i0+tx][d0+r]
            unsigned short h = bf16_rn(v);
            unsigned short lo = bf16_rn(v - bf2f(h));
            unsigned short* row = Mbig + (size_t)(d0 + r) * GK + i0 + tx;
            row[0] = h; row[DM] = h; row[2 * DM] = lo;
        }
    } else if (bid < 144 + 3072) {
        int p = (bid - 144) * 256 + t;                 // pair index
        int s = p / (DM / 2), i = (p % (DM / 2)) * 2;
        float2 v = *(const float2*)&x[(size_t)s * DM + i];
        unsigned short h0 = bf16_rn(v.x);
        unsigned short l0 = bf16_rn(v.x - bf2f(h0));
        unsigned short h1 = bf16_rn(v.y);
        unsigned short l1 = bf16_rn(v.y - bf2f(h1));
        unsigned short* row = Xbig + (size_t)s * GK + i;
        ushort2 hh; hh.x = h0; hh.y = h1;
        ushort2 ll; ll.x = l0; ll.y = l1;
        *(ushort2*)(row)          = hh;
        *(ushort2*)(row + DM)     = ll;
        *(ushort2*)(row + 2 * DM) = hh;
    } else if (bid < 3516) {
        int tid = (bid - 3216) * 256 + t;
        if (tid < ST * DM) {
            int d = tid / ST, j = tid % ST;
            float s = 0.f;
#pragma unroll
            for (int k = 0; k < KF; ++k)
                s += (C[j * 2 * KF + k] + C[j * 2 * KF + KF + k]) * Mf[k * DM + d];
            WpT[tid] = s;
        }
        if (tid < DM) {
            float s = 0.f;
#pragma unroll
            for (int k = 0; k < KF; ++k)
                s += (Dv[k] + Dv[KF + k]) * Mf[k * DM + tid];
            evec[tid] = s;
        }
    } else {
        if (t < ST) {
            float a = Av[t];
            float p = 1.f;
            for (int dlt = 0; dlt <= 64; ++dlt) { Apow[dlt * ST + t] = p; p *= a; }
        }
    }
}

// ---------------------------------------------------------------------------
// tables: Kmat[delta][d] = sum_j B_j A_j^delta WpT[d][j]  (64x768 fp32)
//         Ehi/Elo[t][j]  = split(A_j^(t+1))               (64x128 bf16)
//         Qhi/Qlo[j][i]  = split(B_j A_j^(63-i))          (112x64 bf16)
// ---------------------------------------------------------------------------
__global__ __launch_bounds__(256) void tables(const float* __restrict__ Bv,
                                              const float* __restrict__ Apow,
                                              const float* __restrict__ WpT,
                                              float* __restrict__ Kmat,
                                              unsigned short* __restrict__ Ehi,
                                              unsigned short* __restrict__ Elo,
                                              unsigned short* __restrict__ Qhi,
                                              unsigned short* __restrict__ Qlo) {
    int tid = blockIdx.x * 256 + threadIdx.x;
    if (tid < 64 * DM) {
        int dlt = tid / DM, d = tid % DM;
        float s = 0.f;
        for (int j = 0; j < ST; ++j)
            s += Bv[j] * Apow[dlt * ST + j] * WpT[d * ST + j];
        Kmat[dlt * DM + d] = s;
    } else if (tid < 64 * DM + 64 * KJ) {
        int r = tid - 64 * DM;
        int tt = r >> 7, j = r & 127;
        float v = (j < ST) ? Apow[(tt + 1) * ST + j] : 0.f;
        unsigned short h = bf16_rn(v);
        unsigned short lo = bf16_rn(v - bf2f(h));
        Ehi[tt * KJ + j] = h;
        Elo[tt * KJ + j] = lo;
    } else {
        int r = tid - 64 * DM - 64 * KJ;
        if (r < NJ * 64) {
            int j = r >> 6, i = r & 63;
            float v = (j < ST) ? Bv[j] * Apow[(63 - i) * ST + j] : 0.f;
            unsigned short h = bf16_rn(v);
            unsigned short lo = bf16_rn(v - bf2f(h));
            Qhi[j * 64 + i] = h;
            Qlo[j * 64 + i] = lo;
        }
    }
}

// ---------------------------------------------------------------------------
// MFMA GEMM: ut[d][s] = sum_k Mbig[d][k]*Xbig[s][k]  (= x @ M_inputs, split)
// 64x128 tile (d x s), BK=32, 4 waves each 64d x 32s.  192 blocks.
// ---------------------------------------------------------------------------
__global__ __launch_bounds__(256) void gemm_mfma(const unsigned short* __restrict__ Mbig,
                                                 const unsigned short* __restrict__ Xbig,
                                                 float* __restrict__ ut) {
    __shared__ unsigned short As[64 * APAD];
    __shared__ unsigned short Bs[128 * APAD];
    int t = threadIdx.x;
    int d0 = blockIdx.x * 64;
    int s0 = blockIdx.y * 128;
    int wave = t >> 6, lane = t & 63;
    int wn = wave * 32;
    int m16 = lane & 15, quad = lane >> 4;
    float4v acc[4][2];
#pragma unroll
    for (int mt = 0; mt < 4; ++mt)
#pragma unroll
        for (int nt = 0; nt < 2; ++nt) acc[mt][nt] = (float4v){0.f, 0.f, 0.f, 0.f};
    for (int k0 = 0; k0 < GK; k0 += GBK) {
#pragma unroll
        for (int it = 0; it < 3; ++it) {
            int idx = t + it * 256;
            int row = idx >> 2, koff = (idx & 3) * 8;
            if (row < 64)
                *(uint4*)&As[row * APAD + koff] =
                    *(const uint4*)&Mbig[(size_t)(d0 + row) * GK + k0 + koff];
            else
                *(uint4*)&Bs[(row - 64) * APAD + koff] =
                    *(const uint4*)&Xbig[(size_t)(s0 + row - 64) * GK + k0 + koff];
        }
        __syncthreads();
        short8 af[4], bf[2];
#pragma unroll
        for (int mt = 0; mt < 4; ++mt)
            af[mt] = *(short8*)&As[(mt * 16 + m16) * APAD + quad * 8];
#pragma unroll
        for (int nt = 0; nt < 2; ++nt)
            bf[nt] = *(short8*)&Bs[(wn + nt * 16 + m16) * APAD + quad * 8];
#pragma unroll
        for (int mt = 0; mt < 4; ++mt)
#pragma unroll
            for (int nt = 0; nt < 2; ++nt)
                acc[mt][nt] = __builtin_amdgcn_mfma_f32_16x16x32_bf16(af[mt], bf[nt], acc[mt][nt], 0, 0, 0);
        __syncthreads();
    }
#pragma unroll
    for (int mt = 0; mt < 4; ++mt)
#pragma unroll
        for (int nt = 0; nt < 2; ++nt) {
            int dd = d0 + mt * 16 + quad * 4;
            int ss = s0 + wn + nt * 16 + m16;
#pragma unroll
            for (int i = 0; i < 4; ++i)
                ut[(size_t)(dd + i) * SEQ + ss] = acc[mt][nt][i];
        }
}

// ---------------------------------------------------------------------------
// hscanG: hloc GEMM (ut rows x Q) + 32-step chunk scan + G write.
// Block = 64 rows of ut-as-(24576x64) = 2 channels x 32 chunks. 384 blocks.
// hloc[m=(d,c)][j] = sum_i u[d,c*64+i] * Q[j][i]; then per j:
//   hs_{c+1} = A^64 hs_c + hloc[c];  G[c][d][j] = split(w_jd * hs_c).
// ---------------------------------------------------------------------------
__global__ __launch_bounds__(256) void hscanG(const float* __restrict__ ut,
                                              const unsigned short* __restrict__ Qhi,
                                              const unsigned short* __restrict__ Qlo,
                                              const float* __restrict__ WpT,
                                              const float* __restrict__ Apow,
                                              unsigned short* __restrict__ Ghi,
                                              unsigned short* __restrict__ Glo) {
    __shared__ float hl[64][120];
    int m0 = blockIdx.x * 64;
    int wave = threadIdx.x >> 6, lane = threadIdx.x & 63;
    int m16 = lane & 15, quad = lane >> 4;
    float4v acc[7];
#pragma unroll
    for (int nt = 0; nt < 7; ++nt) acc[nt] = (float4v){0.f, 0.f, 0.f, 0.f};
#pragma unroll
    for (int ks = 0; ks < 2; ++ks) {
        const float* ap = ut + (size_t)(m0 + wave * 16 + m16) * 64 + ks * 32 + quad * 8;
        float4 a0 = *(const float4*)ap;
        float4 a1 = *(const float4*)(ap + 4);
        float av[8] = {a0.x, a0.y, a0.z, a0.w, a1.x, a1.y, a1.z, a1.w};
        short8 ah, al;
#pragma unroll
        for (int q = 0; q < 8; ++q) {
            unsigned short h = bf16_rn(av[q]);
            ah[q] = (short)h;
            al[q] = (short)bf16_rn(av[q] - bf2f(h));
        }
#pragma unroll
        for (int nt = 0; nt < 7; ++nt) {
            int qoff = (nt * 16 + m16) * 64 + ks * 32 + quad * 8;
            short8 bh = *(const short8*)(Qhi + qoff);
            short8 bl = *(const short8*)(Qlo + qoff);
            acc[nt] = __builtin_amdgcn_mfma_f32_16x16x32_bf16(ah, bh, acc[nt], 0, 0, 0);
            acc[nt] = __builtin_amdgcn_mfma_f32_16x16x32_bf16(ah, bl, acc[nt], 0, 0, 0);
            acc[nt] = __builtin_amdgcn_mfma_f32_16x16x32_bf16(al, bh, acc[nt], 0, 0, 0);
        }
    }
#pragma unroll
    for (int nt = 0; nt < 7; ++nt)
#pragma unroll
        for (int i = 0; i < 4; ++i)
            hl[wave * 16 + quad * 4 + i][nt * 16 + m16] = acc[nt][i];
    __syncthreads();

    int j = threadIdx.x & 127, dloc = threadIdx.x >> 7;
    int d = blockIdx.x * 2 + dloc;
    bool ja = (j < ST);
    float a64 = ja ? Apow[64 * ST + j] : 0.f;
    float w   = ja ? WpT[d * ST + j] : 0.f;
    float hs = 0.f;
    for (int c = 0; c < NC; ++c) {
        float g = ja ? (w * hs) : 0.f;
        unsigned short gh = bf16_rn(g);
        unsigned short gl = bf16_rn(g - bf2f(gh));
        size_t go = ((size_t)c * DM + d) * KJ + j;
        Ghi[go] = gh;
        Glo[go] = gl;
        float add = ja ? hl[dloc * 32 + c][j] : 0.f;
        hs = fmaf(a64, hs, add);
    }
}

// ---------------------------------------------------------------------------
// intra: register-resident causal Toeplitz per (d, chunk) + feedthrough.
// 1 wave per block = 2 channels x 32 chunks; u[64],y[64] in VGPRs.
// yintra[d][c*64+t] = sum_{dlt<=t} Kmat[dlt][d]*u[t-dlt] + e_d*u[t]
// ---------------------------------------------------------------------------
__global__ __launch_bounds__(64) void intra(const float* __restrict__ ut,
                                            const float* __restrict__ Kmat,
                                            const float* __restrict__ evec,
                                            float* __restrict__ yintra) {
    int lane = threadIdx.x;
    int d = blockIdx.x * 2 + (lane >> 5);
    int c = lane & 31;
    const float* u = ut + (size_t)d * SEQ + c * 64;
    float uu[64];
#pragma unroll
    for (int q = 0; q < 16; ++q) {
        float4 v = *(const float4*)(u + q * 4);
        uu[q * 4 + 0] = v.x; uu[q * 4 + 1] = v.y;
        uu[q * 4 + 2] = v.z; uu[q * 4 + 3] = v.w;
    }
    float e = evec[d];
    float y[64];
#pragma unroll
    for (int t = 0; t < 64; ++t) y[t] = e * uu[t];
#pragma unroll
    for (int dlt = 0; dlt < 64; ++dlt) {
        float k = Kmat[dlt * DM + d];
#pragma unroll
        for (int t = dlt; t < 64; ++t)
            y[t] = fmaf(k, uu[t - dlt], y[t]);
    }
    float* yo = yintra + (size_t)d * SEQ + c * 64;
#pragma unroll
    for (int q = 0; q < 16; ++q) {
        float4 v = make_float4(y[q * 4 + 0], y[q * 4 + 1], y[q * 4 + 2], y[q * 4 + 3]);
        *(float4*)(yo + q * 4) = v;
    }
}

// ---------------------------------------------------------------------------
// inter: out[c*64+t][d] = (E @ G_c)[t][d] + yintra[d][c*64+t]
// Block = (chunk c, 128-wide d tile): GEMM M=64,N=128,K=128 (bf16-split x3),
// operands loaded direct from global; epilogue adds LDS-transposed yintra.
// ---------------------------------------------------------------------------
__global__ __launch_bounds__(256) void inter(const unsigned short* __restrict__ Ehi,
                                             const unsigned short* __restrict__ Elo,
                                             const unsigned short* __restrict__ Ghi,
                                             const unsigned short* __restrict__ Glo,
                                             const float* __restrict__ yintra,
                                             float* __restrict__ out) {
    __shared__ float yl[64][129];
    int c = blockIdx.x;
    int d0 = blockIdx.y * 128;
    int wave = threadIdx.x >> 6, lane = threadIdx.x & 63;
    int wn = wave * 32;
    int m16 = lane & 15, quad = lane >> 4;
    // stage yintra tile transposed: [t][d]
#pragma unroll
    for (int it = 0; it < 8; ++it) {
        int idx = threadIdx.x + it * 256;       // 0..2047
        int row = idx >> 4, col4 = (idx & 15) * 4;
        float4 v = *(const float4*)&yintra[(size_t)(d0 + row) * SEQ + c * 64 + col4];
        yl[col4 + 0][row] = v.x;
        yl[col4 + 1][row] = v.y;
        yl[col4 + 2][row] = v.z;
        yl[col4 + 3][row] = v.w;
    }
    float4v acc[4][2];
#pragma unroll
    for (int mt = 0; mt < 4; ++mt)
#pragma unroll
        for (int nt = 0; nt < 2; ++nt) acc[mt][nt] = (float4v){0.f, 0.f, 0.f, 0.f};
#pragma unroll
    for (int ks = 0; ks < 4; ++ks) {
        short8 bh[2], bl[2];
#pragma unroll
        for (int nt = 0; nt < 2; ++nt) {
            size_t ga = ((size_t)c * DM + d0 + wn + nt * 16 + m16) * KJ + ks * 32 + quad * 8;
            bh[nt] = *(const short8*)(Ghi + ga);
            bl[nt] = *(const short8*)(Glo + ga);
        }
#pragma unroll
        for (int mt = 0; mt < 4; ++mt) {
            int eo = (mt * 16 + m16) * KJ + ks * 32 + quad * 8;
            short8 ah = *(const short8*)(Ehi + eo);
            short8 al = *(const short8*)(Elo + eo);
#pragma unroll
            for (int nt = 0; nt < 2; ++nt) {
                acc[mt][nt] = __builtin_amdgcn_mfma_f32_16x16x32_bf16(ah, bh[nt], acc[mt][nt], 0, 0, 0);
                acc[mt][nt] = __builtin_amdgcn_mfma_f32_16x16x32_bf16(ah, bl[nt], acc[mt][nt], 0, 0, 0);
                acc[mt][nt] = __builtin_amdgcn_mfma_f32_16x16x32_bf16(al, bh[nt], acc[mt][nt], 0, 0, 0);
            }
        }
    }
    __syncthreads();   // yl ready (loads issued before MFMA loop; ensure visibility)
#pragma unroll
    for (int mt = 0; mt < 4; ++mt)
#pragma unroll
        for (int nt = 0; nt < 2; ++nt) {
            int tt = mt * 16 + quad * 4;
            int dcol = wn + nt * 16 + m16;
#pragma unroll
            for (int i = 0; i < 4; ++i) {
                float v = acc[mt][nt][i] + yl[tt + i][dcol];
                out[(size_t)(c * 64 + tt + i) * DM + d0 + dcol] = v;
            }
        }
}

extern "C" void kernel_launch(void* const* d_in, const int* in_sizes, int n_in,
                              void* d_out, int out_size, void* d_ws, size_t ws_size,
                              hipStream_t stream) {
    const float* x  = (const float*)d_in[0];
    const float* Mi = (const float*)d_in[2];
    const float* Mf = (const float*)d_in[3];
    const float* Av = (const float*)d_in[4];
    const float* Bv = (const float*)d_in[5];
    const float* C  = (const float*)d_in[6];
    const float* Dv = (const float*)d_in[7];
    float* out = (float*)d_out;

    float* ut   = (float*)d_ws;                               // 768*2048
    float* WpT  = ut + (size_t)DM * SEQ;                      // 768*100
    float* ev   = WpT + DM * ST;                              // 768
    float* Apow = ev + DM;                                    // 65*100
    float* Kmat = Apow + 65 * ST;                             // 64*768
    unsigned short* Mbig = (unsigned short*)(Kmat + 64 * DM); // 768*2304
    unsigned short* Xbig = Mbig + (size_t)DM * GK;            // 2048*2304
    float* yintra = (float*)Xbig;                             // alias (Xbig dead after gemm)
    unsigned short* Ehi = Xbig + (size_t)SEQ * GK;            // 64*128
    unsigned short* Elo = Ehi + 64 * KJ;
    unsigned short* Qhi = Elo + 64 * KJ;                      // 112*64
    unsigned short* Qlo = Qhi + NJ * 64;
    unsigned short* Ghi = Qlo + NJ * 64;                      // 32*768*128
    unsigned short* Glo = Ghi + (size_t)NC * DM * KJ;

    prep<<<3517, 256, 0, stream>>>(x, Mi, C, Dv, Mf, Av, Mbig, Xbig, WpT, ev, Apow);
    tables<<<252, 256, 0, stream>>>(Bv, Apow, WpT, Kmat, Ehi, Elo, Qhi, Qlo);
    gemm_mfma<<<dim3(DM / 64, SEQ / 128), 256, 0, stream>>>(Mbig, Xbig, ut);
    hscanG<<<384, 256, 0, stream>>>(ut, Qhi, Qlo, WpT, Apow, Ghi, Glo);
    intra<<<384, 64, 0, stream>>>(ut, Kmat, ev, yintra);
    inter<<<dim3(NC, DM / 128), 256, 0, stream>>>(Ehi, Elo, Ghi, Glo, yintra, out);
}

// Round 5
// 166.033 us; speedup vs baseline: 3.3919x; 1.0740x over previous
//
#include <hip/hip_runtime.h>

#define SEQ   2048
#define DM    768
#define ST    100
#define KF    24
#define L64   64
#define NC    32      // SEQ / L64
#define KJ    128     // padded state dim for inter-GEMM K
#define NJ    112     // padded state dim for hloc-GEMM N
#define GK    2304    // 3 * DM  (bf16x3 split K for input GEMM)
#define KSPLIT 6
#define KCH   (GK / KSPLIT)   // 384

using short8  = __attribute__((ext_vector_type(8))) short;
using float4v = __attribute__((ext_vector_type(4))) float;

__device__ __forceinline__ unsigned short bf16_rn(float x) {
    unsigned int u = __float_as_uint(x);
    unsigned int r = u + 0x7FFFu + ((u >> 16) & 1u);
    return (unsigned short)(r >> 16);
}
__device__ __forceinline__ float bf2f(unsigned short h) {
    return __uint_as_float(((unsigned int)h) << 16);
}
__device__ __forceinline__ void async16(const void* g, void* l) {
    __builtin_amdgcn_global_load_lds(
        (const __attribute__((address_space(1))) unsigned int*)g,
        (__attribute__((address_space(3))) unsigned int*)l, 16, 0, 0);
}
__device__ __forceinline__ void atomAddF(float* p, float v) {
#if __has_builtin(__builtin_amdgcn_global_atomic_fadd_f32)
    __builtin_amdgcn_global_atomic_fadd_f32(
        (__attribute__((address_space(1))) float*)p, v);
#else
    unsafeAtomicAdd(p, v);
#endif
}

// ---------------------------------------------------------------------------
// prep: block ranges:
//  [0,144)      Mbig[d][k] = [Mih^T | Mih^T | Mil^T]
//  [144,912)    Xbig[s][k] = [xh | xl | xh]   (16B stores)
//  [912,1212)   WpT[d][j] = sum_k (C[j,k]+C[j,k+24])*Mf[k,d];  ev[d]
//  [1212]       Apow[delta][j] = A_j^delta, delta = 0..64
//  [1213,2749)  zero ut (accumulated by split-K gemm atomics)
// ---------------------------------------------------------------------------
__global__ __launch_bounds__(256) void prep(const float* __restrict__ x,
                                            const float* __restrict__ Mi,
                                            const float* __restrict__ C,
                                            const float* __restrict__ Dv,
                                            const float* __restrict__ Mf,
                                            const float* __restrict__ Av,
                                            unsigned short* __restrict__ Mbig,
                                            unsigned short* __restrict__ Xbig,
                                            float* __restrict__ WpT,
                                            float* __restrict__ evec,
                                            float* __restrict__ Apow,
                                            float* __restrict__ ut) {
    __shared__ float tl[64][65];
    int bid = blockIdx.x, t = threadIdx.x;
    if (bid < 144) {
        int i0 = (bid / 12) * 64, d0 = (bid % 12) * 64;
        int tx = t & 63, ty = t >> 6;
#pragma unroll
        for (int r = ty; r < 64; r += 4)
            tl[r][tx] = Mi[(i0 + r) * DM + d0 + tx];
        __syncthreads();
#pragma unroll
        for (int r = ty; r < 64; r += 4) {
            float v = tl[tx][r];                       // Mi[i0+tx][d0+r]
            unsigned short h = bf16_rn(v);
            unsigned short lo = bf16_rn(v - bf2f(h));
            unsigned short* row = Mbig + (size_t)(d0 + r) * GK + i0 + tx;
            row[0] = h; row[DM] = h; row[2 * DM] = lo;
        }
    } else if (bid < 912) {
        int idx8 = (bid - 144) * 256 + t;              // 8 elems per thread
        int s = idx8 / (DM / 8), i0 = (idx8 % (DM / 8)) * 8;
        const float* xp = x + (size_t)s * DM + i0;
        float4 v0 = *(const float4*)xp;
        float4 v1 = *(const float4*)(xp + 4);
        float av[8] = {v0.x, v0.y, v0.z, v0.w, v1.x, v1.y, v1.z, v1.w};
        short8 hh, ll;
#pragma unroll
        for (int q = 0; q < 8; ++q) {
            unsigned short h = bf16_rn(av[q]);
            hh[q] = (short)h;
            ll[q] = (short)bf16_rn(av[q] - bf2f(h));
        }
        unsigned short* row = Xbig + (size_t)s * GK + i0;
        *(short8*)(row)          = hh;
        *(short8*)(row + DM)     = ll;
        *(short8*)(row + 2 * DM) = hh;
    } else if (bid < 1212) {
        int tid = (bid - 912) * 256 + t;
        if (tid < ST * DM) {
            int d = tid / ST, j = tid % ST;
            float s = 0.f;
#pragma unroll
            for (int k = 0; k < KF; ++k)
                s += (C[j * 2 * KF + k] + C[j * 2 * KF + KF + k]) * Mf[k * DM + d];
            WpT[tid] = s;
        }
        if (tid < DM) {
            float s = 0.f;
#pragma unroll
            for (int k = 0; k < KF; ++k)
                s += (Dv[k] + Dv[KF + k]) * Mf[k * DM + tid];
            evec[tid] = s;
        }
    } else if (bid == 1212) {
        if (t < ST) {
            float a = Av[t];
            float p = 1.f;
            for (int dlt = 0; dlt <= 64; ++dlt) { Apow[dlt * ST + t] = p; p *= a; }
        }
    } else {
        int idx = (bid - 1213) * 256 + t;
        *(float4*)&ut[(size_t)idx * 4] = make_float4(0.f, 0.f, 0.f, 0.f);
    }
}

// ---------------------------------------------------------------------------
// tables: Kmat[delta][d] = sum_j B_j A_j^delta WpT[d][j]  (64x768 fp32)
//         Ehi/Elo[t][j]  = split(A_j^(t+1))               (64x128 bf16)
//         Qhi/Qlo[j][i]  = split(B_j A_j^(63-i))          (112x64 bf16)
// ---------------------------------------------------------------------------
__global__ __launch_bounds__(256) void tables(const float* __restrict__ Bv,
                                              const float* __restrict__ Apow,
                                              const float* __restrict__ WpT,
                                              float* __restrict__ Kmat,
                                              unsigned short* __restrict__ Ehi,
                                              unsigned short* __restrict__ Elo,
                                              unsigned short* __restrict__ Qhi,
                                              unsigned short* __restrict__ Qlo) {
    int tid = blockIdx.x * 256 + threadIdx.x;
    if (tid < 64 * DM) {
        int dlt = tid / DM, d = tid % DM;
        float s = 0.f;
        for (int j = 0; j < ST; ++j)
            s += Bv[j] * Apow[dlt * ST + j] * WpT[d * ST + j];
        Kmat[dlt * DM + d] = s;
    } else if (tid < 64 * DM + 64 * KJ) {
        int r = tid - 64 * DM;
        int tt = r >> 7, j = r & 127;
        float v = (j < ST) ? Apow[(tt + 1) * ST + j] : 0.f;
        unsigned short h = bf16_rn(v);
        unsigned short lo = bf16_rn(v - bf2f(h));
        Ehi[tt * KJ + j] = h;
        Elo[tt * KJ + j] = lo;
    } else {
        int r = tid - 64 * DM - 64 * KJ;
        if (r < NJ * 64) {
            int j = r >> 6, i = r & 63;
            float v = (j < ST) ? Bv[j] * Apow[(63 - i) * ST + j] : 0.f;
            unsigned short h = bf16_rn(v);
            unsigned short lo = bf16_rn(v - bf2f(h));
            Qhi[j * 64 + i] = h;
            Qlo[j * 64 + i] = lo;
        }
    }
}

// ---------------------------------------------------------------------------
// MFMA GEMM, split-K x6 with fp32 atomics: ut[d][s] += partial.
// 128x128 tile (d x s), BK=32, 2x2 wave grid, global_load_lds staging.
// Grid (96 tiles, 6 k-chunks) = 576 blocks.
// ---------------------------------------------------------------------------
__global__ __launch_bounds__(256) void gemm_mfma(const unsigned short* __restrict__ Mbig,
                                                 const unsigned short* __restrict__ Xbig,
                                                 float* __restrict__ ut) {
    __shared__ unsigned short As[128 * 32];
    __shared__ unsigned short Bs[128 * 32];
    int t = threadIdx.x;
    int tile = blockIdx.x;
    int d0 = (tile % (DM / 128)) * 128;
    int s0 = (tile / (DM / 128)) * 128;
    int k0base = blockIdx.y * KCH;
    int wave = t >> 6, lane = t & 63;
    int wm = (wave & 1) * 64, wn = (wave >> 1) * 64;
    int m16 = lane & 15, quad = lane >> 4;
    // staging indices: idx = t + it*256; row = idx>>2; koff = (idx&3)*8
    int r0 = t >> 2, ko0 = (t & 3) * 8;
    int r1 = (t + 256) >> 2, ko1 = ((t + 256) & 3) * 8;
    float4v acc[4][4];
#pragma unroll
    for (int mt = 0; mt < 4; ++mt)
#pragma unroll
        for (int nt = 0; nt < 4; ++nt) acc[mt][nt] = (float4v){0.f, 0.f, 0.f, 0.f};
    for (int k0 = k0base; k0 < k0base + KCH; k0 += 32) {
        __syncthreads();
        async16(&Mbig[(size_t)(d0 + r0) * GK + k0 + ko0], &As[(size_t)t * 8]);
        async16(&Xbig[(size_t)(s0 + r0) * GK + k0 + ko0], &Bs[(size_t)t * 8]);
        async16(&Mbig[(size_t)(d0 + r1) * GK + k0 + ko1], &As[(size_t)(t + 256) * 8]);
        async16(&Xbig[(size_t)(s0 + r1) * GK + k0 + ko1], &Bs[(size_t)(t + 256) * 8]);
        __syncthreads();
        short8 af[4], bf[4];
#pragma unroll
        for (int mt = 0; mt < 4; ++mt)
            af[mt] = *(short8*)&As[(wm + mt * 16 + m16) * 32 + quad * 8];
#pragma unroll
        for (int nt = 0; nt < 4; ++nt)
            bf[nt] = *(short8*)&Bs[(wn + nt * 16 + m16) * 32 + quad * 8];
#pragma unroll
        for (int mt = 0; mt < 4; ++mt)
#pragma unroll
            for (int nt = 0; nt < 4; ++nt)
                acc[mt][nt] = __builtin_amdgcn_mfma_f32_16x16x32_bf16(af[mt], bf[nt], acc[mt][nt], 0, 0, 0);
    }
#pragma unroll
    for (int mt = 0; mt < 4; ++mt)
#pragma unroll
        for (int nt = 0; nt < 4; ++nt) {
            int dd = d0 + wm + mt * 16 + quad * 4;
            int ss = s0 + wn + nt * 16 + m16;
#pragma unroll
            for (int i = 0; i < 4; ++i)
                atomAddF(&ut[(size_t)(dd + i) * SEQ + ss], acc[mt][nt][i]);
        }
}

// ---------------------------------------------------------------------------
// hscanG: hloc GEMM (ut rows x Q) + 32-step chunk scan + G write.
// Block = 64 rows of ut-as-(24576x64) = 2 channels x 32 chunks. 384 blocks.
// ---------------------------------------------------------------------------
__global__ __launch_bounds__(256) void hscanG(const float* __restrict__ ut,
                                              const unsigned short* __restrict__ Qhi,
                                              const unsigned short* __restrict__ Qlo,
                                              const float* __restrict__ WpT,
                                              const float* __restrict__ Apow,
                                              unsigned short* __restrict__ Ghi,
                                              unsigned short* __restrict__ Glo) {
    __shared__ float hl[64][120];
    int m0 = blockIdx.x * 64;
    int wave = threadIdx.x >> 6, lane = threadIdx.x & 63;
    int m16 = lane & 15, quad = lane >> 4;
    float4v acc[7];
#pragma unroll
    for (int nt = 0; nt < 7; ++nt) acc[nt] = (float4v){0.f, 0.f, 0.f, 0.f};
#pragma unroll
    for (int ks = 0; ks < 2; ++ks) {
        const float* ap = ut + (size_t)(m0 + wave * 16 + m16) * 64 + ks * 32 + quad * 8;
        float4 a0 = *(const float4*)ap;
        float4 a1 = *(const float4*)(ap + 4);
        float av[8] = {a0.x, a0.y, a0.z, a0.w, a1.x, a1.y, a1.z, a1.w};
        short8 ah, al;
#pragma unroll
        for (int q = 0; q < 8; ++q) {
            unsigned short h = bf16_rn(av[q]);
            ah[q] = (short)h;
            al[q] = (short)bf16_rn(av[q] - bf2f(h));
        }
#pragma unroll
        for (int nt = 0; nt < 7; ++nt) {
            int qoff = (nt * 16 + m16) * 64 + ks * 32 + quad * 8;
            short8 bh = *(const short8*)(Qhi + qoff);
            short8 bl = *(const short8*)(Qlo + qoff);
            acc[nt] = __builtin_amdgcn_mfma_f32_16x16x32_bf16(ah, bh, acc[nt], 0, 0, 0);
            acc[nt] = __builtin_amdgcn_mfma_f32_16x16x32_bf16(ah, bl, acc[nt], 0, 0, 0);
            acc[nt] = __builtin_amdgcn_mfma_f32_16x16x32_bf16(al, bh, acc[nt], 0, 0, 0);
        }
    }
#pragma unroll
    for (int nt = 0; nt < 7; ++nt)
#pragma unroll
        for (int i = 0; i < 4; ++i)
            hl[wave * 16 + quad * 4 + i][nt * 16 + m16] = acc[nt][i];
    __syncthreads();

    int j = threadIdx.x & 127, dloc = threadIdx.x >> 7;
    int d = blockIdx.x * 2 + dloc;
    bool ja = (j < ST);
    float a64 = ja ? Apow[64 * ST + j] : 0.f;
    float w   = ja ? WpT[d * ST + j] : 0.f;
    float hs = 0.f;
    for (int c = 0; c < NC; ++c) {
        float g = ja ? (w * hs) : 0.f;
        unsigned short gh = bf16_rn(g);
        unsigned short gl = bf16_rn(g - bf2f(gh));
        size_t go = ((size_t)c * DM + d) * KJ + j;
        Ghi[go] = gh;
        Glo[go] = gl;
        float add = ja ? hl[dloc * 32 + c][j] : 0.f;
        hs = fmaf(a64, hs, add);
    }
}

// ---------------------------------------------------------------------------
// intra: register-resident causal Toeplitz per (d, chunk) + feedthrough.
// ---------------------------------------------------------------------------
__global__ __launch_bounds__(64) void intra(const float* __restrict__ ut,
                                            const float* __restrict__ Kmat,
                                            const float* __restrict__ evec,
                                            float* __restrict__ yintra) {
    int lane = threadIdx.x;
    int d = blockIdx.x * 2 + (lane >> 5);
    int c = lane & 31;
    const float* u = ut + (size_t)d * SEQ + c * 64;
    float uu[64];
#pragma unroll
    for (int q = 0; q < 16; ++q) {
        float4 v = *(const float4*)(u + q * 4);
        uu[q * 4 + 0] = v.x; uu[q * 4 + 1] = v.y;
        uu[q * 4 + 2] = v.z; uu[q * 4 + 3] = v.w;
    }
    float e = evec[d];
    float y[64];
#pragma unroll
    for (int t = 0; t < 64; ++t) y[t] = e * uu[t];
#pragma unroll
    for (int dlt = 0; dlt < 64; ++dlt) {
        float k = Kmat[dlt * DM + d];
#pragma unroll
        for (int t = dlt; t < 64; ++t)
            y[t] = fmaf(k, uu[t - dlt], y[t]);
    }
    float* yo = yintra + (size_t)d * SEQ + c * 64;
#pragma unroll
    for (int q = 0; q < 16; ++q) {
        float4 v = make_float4(y[q * 4 + 0], y[q * 4 + 1], y[q * 4 + 2], y[q * 4 + 3]);
        *(float4*)(yo + q * 4) = v;
    }
}

// ---------------------------------------------------------------------------
// inter: out[c*64+t][d] = (E @ G_c)[t][d] + yintra[d][c*64+t]
// ---------------------------------------------------------------------------
__global__ __launch_bounds__(256) void inter(const unsigned short* __restrict__ Ehi,
                                             const unsigned short* __restrict__ Elo,
                                             const unsigned short* __restrict__ Ghi,
                                             const unsigned short* __restrict__ Glo,
                                             const float* __restrict__ yintra,
                                             float* __restrict__ out) {
    __shared__ float yl[64][129];
    int c = blockIdx.x;
    int d0 = blockIdx.y * 128;
    int wave = threadIdx.x >> 6, lane = threadIdx.x & 63;
    int wn = wave * 32;
    int m16 = lane & 15, quad = lane >> 4;
#pragma unroll
    for (int it = 0; it < 8; ++it) {
        int idx = threadIdx.x + it * 256;
        int row = idx >> 4, col4 = (idx & 15) * 4;
        float4 v = *(const float4*)&yintra[(size_t)(d0 + row) * SEQ + c * 64 + col4];
        yl[col4 + 0][row] = v.x;
        yl[col4 + 1][row] = v.y;
        yl[col4 + 2][row] = v.z;
        yl[col4 + 3][row] = v.w;
    }
    float4v acc[4][2];
#pragma unroll
    for (int mt = 0; mt < 4; ++mt)
#pragma unroll
        for (int nt = 0; nt < 2; ++nt) acc[mt][nt] = (float4v){0.f, 0.f, 0.f, 0.f};
#pragma unroll
    for (int ks = 0; ks < 4; ++ks) {
        short8 bh[2], bl[2];
#pragma unroll
        for (int nt = 0; nt < 2; ++nt) {
            size_t ga = ((size_t)c * DM + d0 + wn + nt * 16 + m16) * KJ + ks * 32 + quad * 8;
            bh[nt] = *(const short8*)(Ghi + ga);
            bl[nt] = *(const short8*)(Glo + ga);
        }
#pragma unroll
        for (int mt = 0; mt < 4; ++mt) {
            int eo = (mt * 16 + m16) * KJ + ks * 32 + quad * 8;
            short8 ah = *(const short8*)(Ehi + eo);
            short8 al = *(const short8*)(Elo + eo);
#pragma unroll
            for (int nt = 0; nt < 2; ++nt) {
                acc[mt][nt] = __builtin_amdgcn_mfma_f32_16x16x32_bf16(ah, bh[nt], acc[mt][nt], 0, 0, 0);
                acc[mt][nt] = __builtin_amdgcn_mfma_f32_16x16x32_bf16(ah, bl[nt], acc[mt][nt], 0, 0, 0);
                acc[mt][nt] = __builtin_amdgcn_mfma_f32_16x16x32_bf16(al, bh[nt], acc[mt][nt], 0, 0, 0);
            }
        }
    }
    __syncthreads();
#pragma unroll
    for (int mt = 0; mt < 4; ++mt)
#pragma unroll
        for (int nt = 0; nt < 2; ++nt) {
            int tt = mt * 16 + quad * 4;
            int dcol = wn + nt * 16 + m16;
#pragma unroll
            for (int i = 0; i < 4; ++i) {
                float v = acc[mt][nt][i] + yl[tt + i][dcol];
                out[(size_t)(c * 64 + tt + i) * DM + d0 + dcol] = v;
            }
        }
}

extern "C" void kernel_launch(void* const* d_in, const int* in_sizes, int n_in,
                              void* d_out, int out_size, void* d_ws, size_t ws_size,
                              hipStream_t stream) {
    const float* x  = (const float*)d_in[0];
    const float* Mi = (const float*)d_in[2];
    const float* Mf = (const float*)d_in[3];
    const float* Av = (const float*)d_in[4];
    const float* Bv = (const float*)d_in[5];
    const float* C  = (const float*)d_in[6];
    const float* Dv = (const float*)d_in[7];
    float* out = (float*)d_out;

    float* ut   = (float*)d_ws;                               // 768*2048
    float* WpT  = ut + (size_t)DM * SEQ;                      // 768*100
    float* ev   = WpT + DM * ST;                              // 768
    float* Apow = ev + DM;                                    // 65*100
    float* Kmat = Apow + 65 * ST;                             // 64*768
    unsigned short* Mbig = (unsigned short*)(Kmat + 64 * DM); // 768*2304
    unsigned short* Xbig = Mbig + (size_t)DM * GK;            // 2048*2304
    float* yintra = (float*)Xbig;                             // alias (Xbig dead after gemm)
    unsigned short* Ehi = Xbig + (size_t)SEQ * GK;            // 64*128
    unsigned short* Elo = Ehi + 64 * KJ;
    unsigned short* Qhi = Elo + 64 * KJ;                      // 112*64
    unsigned short* Qlo = Qhi + NJ * 64;
    unsigned short* Ghi = Qlo + NJ * 64;                      // 32*768*128
    unsigned short* Glo = Ghi + (size_t)NC * DM * KJ;

    prep<<<2749, 256, 0, stream>>>(x, Mi, C, Dv, Mf, Av, Mbig, Xbig, WpT, ev, Apow, ut);
    tables<<<252, 256, 0, stream>>>(Bv, Apow, WpT, Kmat, Ehi, Elo, Qhi, Qlo);
    gemm_mfma<<<dim3((DM / 128) * (SEQ / 128), KSPLIT), 256, 0, stream>>>(Mbig, Xbig, ut);
    hscanG<<<384, 256, 0, stream>>>(ut, Qhi, Qlo, WpT, Apow, Ghi, Glo);
    intra<<<384, 64, 0, stream>>>(ut, Kmat, ev, yintra);
    inter<<<dim3(NC, DM / 128), 256, 0, stream>>>(Ehi, Elo, Ghi, Glo, yintra, out);
}